// Round 6
// baseline (20.269 us; speedup 1.0000x reference)
//
#include <hip/hip_runtime.h>
#include <math.h>

#define NATOMS 32
#define NMOL   64
#define NPAIRS 496     // C(32,2)
#define MAXP   466
#define RCRf 5.2f
#define RCAf 3.5f

// One block per (molecule n, center atom i). 512 threads (8 waves).
// A: tid<32 computes per-atom dv/d/fc/species into LDS.
// B: thread tid<496 decodes candidate pair (j,k), computes (c,sin,dmean,2fc,px).
// C: ballot-based bucket sort (NO atomics): 10 ballots/wave -> per-wave counts
//    s_wc[w][b]; 10-thread colsum -> s_tot; 10-thread prefix -> s_base; each
//    pair-thread computes exact slot = base + cross-wave + lane prefix; b128 write.
// E: tid<320 owns angular feature (bucket=tid>>5, a=(tid>>3)&3, z=tid&7), scans
//    only its bucket (broadcast b128, unroll x2). tid 320-383 own radial features.
__global__ __launch_bounds__(512) void aev_kernel(const int* __restrict__ species,
                                                  const float* __restrict__ coords,
                                                  float* __restrict__ out) {
    const int bid = blockIdx.x;
    const int n = bid >> 5;
    const int i = bid & 31;
    const int tid = threadIdx.x;
    const int wv = tid >> 6;
    const int lane = tid & 63;

    __shared__ float4 s_atom[NATOMS];            // dvx, dvy, dvz, d
    __shared__ float  s_fca[NATOMS], s_fcr[NATOMS];
    __shared__ int    s_sp[NATOMS];
    __shared__ float4 s_pd[MAXP];                // bucket-sorted: c, sin, dmean, fc2
    __shared__ int    s_wc[8][10];               // per-wave bucket counts
    __shared__ int    s_tot[10], s_base[10];

    // ---------- phase A ----------
    if (tid < NATOMS) {
        const float* cb = coords + (size_t)n * NATOMS * 3;
        float dx = cb[tid*3+0] - cb[i*3+0];
        float dy = cb[tid*3+1] - cb[i*3+1];
        float dz = cb[tid*3+2] - cb[i*3+2];
        float d2 = dx*dx + dy*dy + dz*dz;
        float d  = sqrtf(d2 > 0.f ? d2 : 1.f);   // ref's where(d2>0,d2,1) guard
        bool self = (tid == i);
        s_fcr[tid] = (!self && d <= RCRf) ? (0.5f*__cosf(((float)M_PI/RCRf)*d) + 0.5f) : 0.f;
        s_fca[tid] = (!self && d <= RCAf) ? (0.5f*__cosf(((float)M_PI/RCAf)*d) + 0.5f) : 0.f;
        s_atom[tid] = make_float4(dx, dy, dz, d);
        s_sp[tid]   = species[n*NATOMS + tid];
    }
    __syncthreads();

    // ---------- phase B: one candidate pair per thread ----------
    float4 pd;
    int px = -1;
    if (tid < NPAIRS) {
        // closed-form triangular decode: off(j) = j*(63-j)/2
        float t = sqrtf((float)(3969 - 8*tid));
        int j = (int)((63.0f - t) * 0.5f);
        if (j*(63-j)/2 > tid) --j;               // float-rounding fixups
        if ((j+1)*(62-j)/2 <= tid) ++j;
        int k = tid - j*(63-j)/2 + j + 1;
        float fc2 = 2.f * s_fca[j] * s_fca[k];
        if (fc2 > 0.f) {                          // both in RCA, both != i
            float4 aj = s_atom[j], ak = s_atom[k];
            float dot = aj.x*ak.x + aj.y*ak.y + aj.z*ak.z;
            float c = 0.95f * dot * __builtin_amdgcn_rcpf(aj.w * ak.w);
            c = fminf(0.95f, fmaxf(-0.95f, c));
            float s = sqrtf(1.f - c*c);           // sin(acos(c))
            float dmean = 0.5f * (aj.w + ak.w);
            int sj = s_sp[j], sk = s_sp[k];
            int lo = min(sj, sk), hi = max(sj, sk);
            px = ((lo*(9-lo)) >> 1) + (hi - lo);  // triu pair index, S=4
            pd = make_float4(c, s, dmean, fc2);
        }
    }

    // ---------- phase C: ballot bucket-sort (no atomics) ----------
    const unsigned long long ltm = (lane == 63) ? ~0ull >> 1
                                                : ((1ull << lane) - 1ull);
    int myprefix = 0;
    #pragma unroll
    for (int b = 0; b < 10; ++b) {
        unsigned long long m = __ballot(px == b);   // full-wave context
        if (px == b)   myprefix = (int)__popcll(m & ltm);
        if (lane == b) s_wc[wv][b] = (int)__popcll(m);
    }
    __syncthreads();
    if (tid < 10) {
        int t = 0;
        #pragma unroll
        for (int w = 0; w < 8; ++w) t += s_wc[w][tid];
        s_tot[tid] = t;
    }
    __syncthreads();
    if (tid < 10) {
        int b = 0;
        for (int t = 0; t < tid; ++t) b += s_tot[t];
        s_base[tid] = b;
    }
    __syncthreads();
    if (px >= 0) {
        int pos = s_base[px] + myprefix;
        #pragma unroll
        for (int w = 0; w < 7; ++w) if (w < wv) pos += s_wc[w][px];
        s_pd[pos] = pd;
    }
    __syncthreads();

    // ---------- phase E: per-feature accumulation ----------
    float* oa = out + NMOL*NATOMS + (size_t)bid * 384;

    if (tid < 320) {
        const int b = tid >> 5;
        const int a = (tid >> 3) & 3;
        const int z = tid & 7;
        const float sha  = 0.9f + 0.65f * (float)a;                          // SHF_A
        const float zang = (float)z * ((float)M_PI/8.f) + (float)M_PI/16.f;  // SHF_Z
        const float czv = __cosf(zang), szv = __sinf(zang);
        const int p0 = s_base[b];
        const int pe = p0 + s_tot[b];

        float acc = 0.f;
        int p = p0;
        for (; p + 1 < pe; p += 2) {                 // unroll x2: pipeline b128 loads
            float4 d0 = s_pd[p];
            float4 d1 = s_pd[p+1];
            float dm0 = d0.z - sha;
            float f0  = __expf(-8.f*dm0*dm0) * d0.w;
            float cd0 = d0.x*czv + d0.y*szv;
            float x0  = 0.5f + 0.5f*cd0;
            float q0 = x0*x0; q0 *= q0; q0 *= q0; q0 *= q0; q0 *= q0;  // ^32
            acc += f0 * q0;
            float dm1 = d1.z - sha;
            float f1  = __expf(-8.f*dm1*dm1) * d1.w;
            float cd1 = d1.x*czv + d1.y*szv;
            float x1  = 0.5f + 0.5f*cd1;
            float q1 = x1*x1; q1 *= q1; q1 *= q1; q1 *= q1; q1 *= q1;
            acc += f1 * q1;
        }
        if (p < pe) {
            float4 d0 = s_pd[p];
            float dm0 = d0.z - sha;
            float f0  = __expf(-8.f*dm0*dm0) * d0.w;
            float cd0 = d0.x*czv + d0.y*szv;
            float x0  = 0.5f + 0.5f*cd0;
            float q0 = x0*x0; q0 *= q0; q0 *= q0; q0 *= q0; q0 *= q0;
            acc += f0 * q0;
        }
        oa[64 + tid] = acc;
    } else if (tid < 384) {
        const int f  = tid - 320;
        const int rs = f >> 4;
        const float shr = 0.9f + 0.26875f * (float)(f & 15);   // SHF_R
        float racc = 0.f;
        #pragma unroll 8
        for (int j = 0; j < NATOMS; ++j) {
            float d = s_atom[j].w, fr = s_fcr[j];    // fr==0 encodes mask
            float dmr = d - shr;
            racc += (s_sp[j] == rs) ? 0.25f * __expf(-16.f*dmr*dmr) * fr : 0.f;
        }
        oa[f] = racc;
        if (f == 0) out[bid] = (float)s_sp[i];       // output 0: species
    }
}

extern "C" void kernel_launch(void* const* d_in, const int* in_sizes, int n_in,
                              void* d_out, int out_size, void* d_ws, size_t ws_size,
                              hipStream_t stream) {
    const int*   species = (const int*)d_in[0];
    const float* coords  = (const float*)d_in[1];
    float*       out     = (float*)d_out;
    aev_kernel<<<NMOL * NATOMS, 512, 0, stream>>>(species, coords, out);
}

// Round 7
// 16.099 us; speedup vs baseline: 1.2590x; 1.2590x over previous
//
#include <hip/hip_runtime.h>
#include <math.h>

#define NATOMS 32
#define NMOL   64
#define MAXP   466     // >= C(31,2)=465
#define RCRf 5.2f
#define RCAf 3.5f

// One block per (molecule n, center atom i). 384 threads (6 waves).
// A: tid<32 computes per-atom dv/d/fc/species; wave 0 ballot-compacts the
//    in-RCA neighbor list s_nbr[0..nn).
// B1: threads decode candidate pair p in COMPACTED space (cnt=nn(nn-1)/2 ~45 avg),
//     compute species-pair bucket px, histogram via LDS atomics (proven cheap in R5).
// B2: per valid pair, compute (c,s,dmean,fc2) once, then the FACTORIZED features:
//     f1[z]=((1+cos(th-sz))/2)^32 (8 values), f2f[a]=2*fc*exp(-8(dm-sha)^2) (4),
//     store 12 floats bucket-sorted via atomic slot (3x ds_write_b128).
// E: tid<320 owns angular feature (b,a,z): acc += f1[z]*f2f[a] over its bucket
//    (2x ds_read_b32 + fma per pair). tid 320..383 own the 64 radial features.
__global__ __launch_bounds__(384) void aev_kernel(const int* __restrict__ species,
                                                  const float* __restrict__ coords,
                                                  float* __restrict__ out) {
    const int bid = blockIdx.x;
    const int n = bid >> 5;
    const int i = bid & 31;
    const int tid = threadIdx.x;

    __shared__ float4 s_atom[NATOMS];            // dvx, dvy, dvz, d
    __shared__ float  s_fca[NATOMS], s_fcr[NATOMS];
    __shared__ int    s_sp[NATOMS];
    __shared__ int    s_nbr[NATOMS];
    __shared__ int    s_nn;
    __shared__ __align__(16) float s_rec[MAXP*12];   // per pair: f1[0..7], f2f[0..3]
    __shared__ int    s_cnt[10], s_base[10], s_ofs[10];

    if (tid < 10) s_cnt[tid] = 0;

    // ---------- phase A + neighbor compaction (wave 0) ----------
    if (tid < 64) {
        float fca_v = 0.f;
        if (tid < NATOMS) {
            const float* cb = coords + (size_t)n*NATOMS*3;
            float dx = cb[tid*3+0] - cb[i*3+0];
            float dy = cb[tid*3+1] - cb[i*3+1];
            float dz = cb[tid*3+2] - cb[i*3+2];
            float d2 = dx*dx + dy*dy + dz*dz;
            float d  = sqrtf(d2 > 0.f ? d2 : 1.f);   // ref's where(d2>0,d2,1) guard
            bool self = (tid == i);
            s_fcr[tid] = (!self && d <= RCRf) ? (0.5f*__cosf(((float)M_PI/RCRf)*d) + 0.5f) : 0.f;
            fca_v      = (!self && d <= RCAf) ? (0.5f*__cosf(((float)M_PI/RCAf)*d) + 0.5f) : 0.f;
            s_fca[tid]  = fca_v;
            s_atom[tid] = make_float4(dx, dy, dz, d);
            s_sp[tid]   = species[n*NATOMS + tid];
        }
        unsigned long long m = __ballot(fca_v > 0.f);  // full-wave-active context
        if (fca_v > 0.f) s_nbr[__popcll(m & ((1ull << tid) - 1ull))] = tid;
        if (tid == 0) s_nn = (int)__popcll(m);
    }
    __syncthreads();

    const int nn  = s_nn;
    const int cnt = (nn*(nn-1)) >> 1;
    const int M   = 2*nn - 1;

    // ---------- B1: pair decode (compacted space) + histogram ----------
    int pj[2] = {-1, -1}, pk[2], ppx[2];
    #pragma unroll
    for (int rep = 0; rep < 2; ++rep) {
        int p = tid + rep*384;
        if (p < cnt) {
            float t = sqrtf((float)(M*M - 8*p));
            int jj = (int)(((float)M - t) * 0.5f);
            while (jj*(2*nn-jj-1)/2 > p) --jj;              // float-rounding fixups
            while ((jj+1)*(2*nn-jj-2)/2 <= p) ++jj;
            int kk = p - jj*(2*nn-jj-1)/2 + jj + 1;
            int j = s_nbr[jj], k = s_nbr[kk];
            int sj = s_sp[j], sk = s_sp[k];
            int lo = min(sj, sk), hi = max(sj, sk);
            int px = ((lo*(9-lo)) >> 1) + (hi - lo);        // triu pair index, S=4
            pj[rep] = j; pk[rep] = k; ppx[rep] = px;
            atomicAdd(&s_cnt[px], 1);
        }
    }
    __syncthreads();

    if (tid == 0) {
        int run = 0;
        #pragma unroll
        for (int b = 0; b < 10; ++b) { s_base[b] = run; s_ofs[b] = run; run += s_cnt[b]; }
    }
    __syncthreads();

    // ---------- B2: factorized pair features -> bucket-sorted LDS ----------
    const float CZ[8] = { 0.98078528f,  0.83146961f,  0.55557023f,  0.19509032f,
                         -0.19509032f, -0.55557023f, -0.83146961f, -0.98078528f};
    const float SZ[8] = { 0.19509032f,  0.55557023f,  0.83146961f,  0.98078528f,
                          0.98078528f,  0.83146961f,  0.55557023f,  0.19509032f};
    const float SHA[4] = {0.9f, 1.55f, 2.2f, 2.85f};

    #pragma unroll
    for (int rep = 0; rep < 2; ++rep) {
        if (pj[rep] >= 0) {
            int j = pj[rep], k = pk[rep];
            float4 aj = s_atom[j], ak = s_atom[k];
            float fc2 = 2.f * s_fca[j] * s_fca[k];
            float dot = aj.x*ak.x + aj.y*ak.y + aj.z*ak.z;
            float c = 0.95f * dot * __builtin_amdgcn_rcpf(aj.w * ak.w);
            c = fminf(0.95f, fmaxf(-0.95f, c));
            float s = sqrtf(1.f - c*c);                     // sin(acos(c))
            float dmean = 0.5f * (aj.w + ak.w);
            float f1[8], f2f[4];
            #pragma unroll
            for (int z = 0; z < 8; ++z) {
                float x = 0.5f + 0.5f*(c*CZ[z] + s*SZ[z]);  // (1+cos(th-sz))/2
                float q = x*x; q *= q; q *= q; q *= q; q *= q;  // x^32
                f1[z] = q;
            }
            #pragma unroll
            for (int a = 0; a < 4; ++a) {
                float dm = dmean - SHA[a];
                f2f[a] = __expf(-8.f*dm*dm) * fc2;
            }
            int slot = atomicAdd(&s_ofs[ppx[rep]], 1);
            float* r = &s_rec[slot*12];
            *(float4*)(r+0) = make_float4(f1[0], f1[1], f1[2], f1[3]);
            *(float4*)(r+4) = make_float4(f1[4], f1[5], f1[6], f1[7]);
            *(float4*)(r+8) = make_float4(f2f[0], f2f[1], f2f[2], f2f[3]);
        }
    }
    __syncthreads();

    // ---------- E: per-feature accumulation ----------
    float* oa = out + NMOL*NATOMS + (size_t)bid * 384;

    if (tid < 320) {
        const int b = tid >> 5;
        const int a = (tid >> 3) & 3;
        const int z = tid & 7;
        const int p0 = s_base[b];
        const int pe = p0 + s_cnt[b];
        float acc = 0.f;
        #pragma unroll 4
        for (int p = p0; p < pe; ++p)
            acc += s_rec[p*12 + z] * s_rec[p*12 + 8 + a];
        oa[64 + tid] = acc;
    } else {
        const int f  = tid - 320;
        const int rs = f >> 4;
        const float shr = 0.9f + 0.26875f * (float)(f & 15);   // SHF_R
        float racc = 0.f;
        #pragma unroll 8
        for (int j = 0; j < NATOMS; ++j) {
            float d = s_atom[j].w, fr = s_fcr[j];    // fr==0 encodes mask
            float dmr = d - shr;
            racc += (s_sp[j] == rs) ? 0.25f * __expf(-16.f*dmr*dmr) * fr : 0.f;
        }
        oa[f] = racc;
        if (f == 0) out[bid] = (float)s_sp[i];       // output 0: species
    }
}

extern "C" void kernel_launch(void* const* d_in, const int* in_sizes, int n_in,
                              void* d_out, int out_size, void* d_ws, size_t ws_size,
                              hipStream_t stream) {
    const int*   species = (const int*)d_in[0];
    const float* coords  = (const float*)d_in[1];
    float*       out     = (float*)d_out;
    aev_kernel<<<NMOL * NATOMS, 384, 0, stream>>>(species, coords, out);
}